// Round 13
// baseline (235.346 us; speedup 1.0000x reference)
//
#include <hip/hip_runtime.h>
#include <hip/hip_bf16.h>

// Problem constants (B=4, T=4096, C=1024, H=128)
#define T_SEQ 4096
#define NBATCH 4
#define C_EMB 1024
#define H_DIM 128
#define M_ROWS (NBATCH * T_SEQ)   // 16384
#define SPLIT 4                   // j-chunks per Q-tile (flash split-K)

typedef __bf16 bf16x8 __attribute__((ext_vector_type(8)));
typedef float  floatx4 __attribute__((ext_vector_type(4)));

__device__ __forceinline__ ushort f2bf(float f) {
    __hip_bfloat16 h = __float2bfloat16(f);
    return *reinterpret_cast<ushort*>(&h);
}
__device__ __forceinline__ float bf2f(ushort u) {
    unsigned int v = ((unsigned int)u) << 16;
    return *reinterpret_cast<float*>(&v);
}
__device__ __forceinline__ uint4 pack8(const float4& a, const float4& b) {
    __hip_bfloat162 h0 = __float22bfloat162_rn(make_float2(a.x, a.y));
    __hip_bfloat162 h1 = __float22bfloat162_rn(make_float2(a.z, a.w));
    __hip_bfloat162 h2 = __float22bfloat162_rn(make_float2(b.x, b.y));
    __hip_bfloat162 h3 = __float22bfloat162_rn(make_float2(b.z, b.w));
    uint4 r;
    r.x = *reinterpret_cast<unsigned int*>(&h0);
    r.y = *reinterpret_cast<unsigned int*>(&h1);
    r.z = *reinterpret_cast<unsigned int*>(&h2);
    r.w = *reinterpret_cast<unsigned int*>(&h3);
    return r;
}
// Async global->LDS, 16 B/lane. LDS dst is wave-uniform base + lane*16.
__device__ __forceinline__ void gld16(const ushort* g, ushort* l) {
    __builtin_amdgcn_global_load_lds(
        (const __attribute__((address_space(1))) unsigned int*)(g),
        (__attribute__((address_space(3))) unsigned int*)(l),
        16, 0, 0);
}

// ---------------------------------------------------------------------------
// Kernel 0: transpose weights fp32 [C][H] -> bf16 Wt[z][H][K=C]. (R12 tiled)
// ---------------------------------------------------------------------------
__global__ __launch_bounds__(256) void transpose_w(
    const float* __restrict__ Wk, const float* __restrict__ Wq,
    const float* __restrict__ Wv, ushort* __restrict__ wt) {
    const int z = blockIdx.z;
    const float* W = (z == 0) ? Wk : (z == 1) ? Wq : Wv;
    const int k0 = blockIdx.x * 64;
    const int n0 = blockIdx.y * 64;

    __shared__ ushort tile[64][72];   // [k-local][n-local], +8 pad

    const int tid = threadIdx.x;
    const int c4 = tid & 15;
    const int rg = tid >> 4;
#pragma unroll
    for (int i = 0; i < 4; ++i) {
        int r = rg * 4 + i;
        float4 v = *reinterpret_cast<const float4*>(
            W + (size_t)(k0 + r) * H_DIM + n0 + c4 * 4);
        tile[r][c4 * 4 + 0] = f2bf(v.x);
        tile[r][c4 * 4 + 1] = f2bf(v.y);
        tile[r][c4 * 4 + 2] = f2bf(v.z);
        tile[r][c4 * 4 + 3] = f2bf(v.w);
    }
    __syncthreads();
    ushort* Wtz = wt + (size_t)z * H_DIM * C_EMB;
#pragma unroll
    for (int o = 0; o < 2; ++o) {
        int linear = o * 256 + tid;        // [0,512)
        int nl = linear >> 3;              // 0..63
        int kc = linear & 7;               // uint4 chunk (8 k)
        ushort e[8];
#pragma unroll
        for (int j = 0; j < 8; ++j) e[j] = tile[kc * 8 + j][nl];
        uint4 pk;
        pk.x = (unsigned int)e[0] | ((unsigned int)e[1] << 16);
        pk.y = (unsigned int)e[2] | ((unsigned int)e[3] << 16);
        pk.z = (unsigned int)e[4] | ((unsigned int)e[5] << 16);
        pk.w = (unsigned int)e[6] | ((unsigned int)e[7] << 16);
        *reinterpret_cast<uint4*>(
            Wtz + (size_t)(n0 + nl) * C_EMB + k0 + kc * 8) = pk;
    }
}

// ---------------------------------------------------------------------------
// Kernel 1: fused QKV GEMM, 2-phase double-buffered staging (R5-exact,
// the 28.4 us measured version).
// ---------------------------------------------------------------------------
__global__ __launch_bounds__(512, 1) void qkv_gemm(
    const float* __restrict__ x, const ushort* __restrict__ wt,
    ushort* __restrict__ kqv) {
    const int m0 = blockIdx.x * 64;

    __shared__ ushort As[2][64 * 64];     // 2 x 8 KB
    __shared__ ushort Bs[2][384 * 64];    // 2 x 48 KB

    const int tid  = threadIdx.x;
    const int lane = tid & 63;
    const int wave = tid >> 6;          // 0..7
    const int l15  = lane & 15;
    const int quad = lane >> 4;
    const int mg   = (wave >> 1) * 16;  // m sub-block: 0/16/32/48
    const int nb   = (wave & 1) * 12;   // first 16-col n-block: 0 or 12

    floatx4 acc[12];
#pragma unroll
    for (int nj = 0; nj < 12; ++nj) acc[nj] = floatx4{0.f, 0.f, 0.f, 0.f};

    // A-path: thread covers row ar, chunk ac (8 floats per kt)
    const int ar = tid >> 3;            // 0..63
    const int ac = tid & 7;             // 0..7
    const int chp = ac ^ (ar & 7);      // XOR-swizzled chunk
    const float* xrow = x + (size_t)(m0 + ar) * C_EMB + ac * 8;

    // ---- prologue: stage kt=0 into buffer 0 ----
    float4 xa = *reinterpret_cast<const float4*>(xrow);
    float4 xb = *reinterpret_cast<const float4*>(xrow + 4);
#pragma unroll
    for (int i = 0; i < 6; ++i) {
        int rbase = wave * 48 + i * 8;
        int row = rbase + (lane >> 3);
        int chg = (lane & 7) ^ (row & 7);
        gld16(wt + (size_t)row * C_EMB + chg * 8, Bs[0] + rbase * 64);
    }
    *reinterpret_cast<uint4*>(As[0] + ar * 64 + chp * 8) = pack8(xa, xb);
    __syncthreads();   // drains vmcnt (B0) + lgkm (A0) -> buffer 0 ready
    // x regs for kt=1
    xa = *reinterpret_cast<const float4*>(xrow + 64);
    xb = *reinterpret_cast<const float4*>(xrow + 68);

    for (int kt = 0; kt < 16; ++kt) {
        const int cur = kt & 1;

        // ---- stage kt+1 into the other buffer (async; lands by next barrier)
        if (kt < 15) {
#pragma unroll
            for (int i = 0; i < 6; ++i) {
                int rbase = wave * 48 + i * 8;
                int row = rbase + (lane >> 3);
                int chg = (lane & 7) ^ (row & 7);
                gld16(wt + (size_t)row * C_EMB + (kt + 1) * 64 + chg * 8,
                      Bs[cur ^ 1] + rbase * 64);
            }
            // A: regs loaded during previous iteration's compute
            *reinterpret_cast<uint4*>(As[cur ^ 1] + ar * 64 + chp * 8) = pack8(xa, xb);
        }
        // issue x loads for kt+2 (latency hides under this kt's MFMA phase)
        if (kt < 14) {
            const float* nsrc = xrow + (kt + 2) * 64;
            xa = *reinterpret_cast<const float4*>(nsrc);
            xb = *reinterpret_cast<const float4*>(nsrc + 4);
        }

        // ---- compute on buffer cur ----
#pragma unroll
        for (int kk = 0; kk < 2; ++kk) {
            bf16x8 a = *reinterpret_cast<const bf16x8*>(
                As[cur] + (mg + l15) * 64 + ((4 * kk + quad) ^ (l15 & 7)) * 8);
#pragma unroll
            for (int nj = 0; nj < 12; ++nj) {
                int brow = (nb + nj) * 16 + l15;
                bf16x8 b = *reinterpret_cast<const bf16x8*>(
                    Bs[cur] + brow * 64 + ((4 * kk + quad) ^ (brow & 7)) * 8);
                acc[nj] = __builtin_amdgcn_mfma_f32_16x16x32_bf16(a, b, acc[nj], 0, 0, 0);
            }
        }

        __syncthreads();   // drains next tile's gld16 + ds_writes; reads done
    }

    // epilogue: z = gcol>>7 is uniform per nj (16-col blocks never straddle)
    const int rowb = m0 + mg + quad * 4;
#pragma unroll
    for (int nj = 0; nj < 12; ++nj) {
        int gcol = (nb + nj) * 16 + l15;
        int z = gcol >> 7;
        int cz = gcol & 127;
        if (z < 2) {
            const float scale = (z == 0) ? 0.03125f : 1.0f;   // fold C^-0.5 into k
            ushort* outz = kqv + (size_t)z * M_ROWS * H_DIM;
#pragma unroll
            for (int r = 0; r < 4; ++r)
                outz[(size_t)(rowb + r) * H_DIM + cz] = f2bf(acc[nj][r] * scale);
        } else {
            ushort* vt = kqv + (size_t)2 * M_ROWS * H_DIM;
            int bb   = rowb >> 12;
            int tloc = rowb & (T_SEQ - 1);
            ushort4 pk;
            pk.x = f2bf(acc[nj][0]);
            pk.y = f2bf(acc[nj][1]);
            pk.z = f2bf(acc[nj][2]);
            pk.w = f2bf(acc[nj][3]);
            *reinterpret_cast<ushort4*>(
                vt + ((size_t)(bb * H_DIM + cz) << 12) + tloc) = pk;
        }
    }
}

// ---------------------------------------------------------------------------
// Kernel 2: flash attention chunks (split-K), ONE-BARRIER-PER-TILE version.
// LDS-budget insight: dropping Vs (16 KB) pays exactly for K double-buffer
// (2x16 KB) -> LDS stays 41984 B -> 3 blocks/CU kept (R1's dbuf failure was
// the occupancy loss, not dbuf itself). Per tile: barrier (cold) -> issue
// K(jt+4) gld16 into spare buffer -> issue all 16 V B-fragments as PLAIN
// LOCAL register loads (static unrolled indices; no R4 lambda/scratch trap)
// -> QK^T from LDS -> softmax -> PV consumes vb with its vmcnt wait ~800 cy
// after issue (fully overlapped). V direct = 4x L2 reads (no cross-wave
// sharing), well under the 34.5 TB/s L2 ceiling. LPT + T5 setprio kept.
// ---------------------------------------------------------------------------
#define P_STRIDE 72
__global__ __launch_bounds__(256, 3) void flash_chunk(
    const ushort* __restrict__ kqv, ushort* __restrict__ partO,
    float* __restrict__ partML) {
    const int it = 63 - (blockIdx.x >> 2);   // LPT: biggest chunks first
    const int c  = blockIdx.x & 3;
    if (c > it) return;                 // block-uniform early out
    const int b  = blockIdx.y;
    const int i0 = it * 64;

    const ushort* Qg = kqv + (size_t)b * T_SEQ * H_DIM;                          // k proj (query role)
    const ushort* Kg = kqv + (size_t)M_ROWS * H_DIM + (size_t)b * T_SEQ * H_DIM; // q proj (key role)
    const ushort* Vt = kqv + (size_t)2 * M_ROWS * H_DIM + (size_t)b * H_DIM * T_SEQ; // vT[h][t]

    __shared__ ushort Ks[2][64 * 128];   // 32 KB double-buffered K
    __shared__ ushort Ps[4][16 * P_STRIDE];   // 9 KB

    const int tid  = threadIdx.x;
    const int lane = tid & 63;
    const int wave = tid >> 6;
    const int l15  = lane & 15;
    const int quad = lane >> 4;

    // Q fragments: row = i0 + wave*16 + l15, k = kk*32 + quad*8
    bf16x8 q[4];
    {
        const ushort* qrow = Qg + (size_t)(i0 + wave * 16 + l15) * H_DIM + quad * 8;
#pragma unroll
        for (int kk = 0; kk < 4; ++kk)
            q[kk] = *reinterpret_cast<const bf16x8*>(qrow + kk * 32);
    }

    float m_i[4], l_i[4];
#pragma unroll
    for (int r = 0; r < 4; ++r) { m_i[r] = -1e30f; l_i[r] = 0.f; }
    floatx4 o[8];
#pragma unroll
    for (int nh = 0; nh < 8; ++nh) o[nh] = floatx4{0.f, 0.f, 0.f, 0.f};

    ushort* Pw = Ps[wave];
    // V fragment base: vb[kp][nh] = Vt[(nh*16+l15)][j0 + kp*32 + quad*8 ..+8]
    const ushort* Vbase = Vt + (size_t)l15 * T_SEQ + quad * 8;

    // K staging geometry (per wave): rows wave*16+i*4 .. +3
    const int krow = lane >> 4;               // 0..3 within 4-row group
    const int kchg = (lane & 15);             // chunk id pre-XOR

    // ---- prologue: stage K(c) into Ks[0] ----
    {
        const int j0s = c * 64;
#pragma unroll
        for (int i = 0; i < 4; ++i) {
            int row = wave * 16 + i * 4 + krow;
            int chg = kchg ^ (row & 15);
            gld16(Kg + (size_t)(j0s + row) * H_DIM + chg * 8,
                  Ks[0] + (wave * 16 + i * 4) * 128);
        }
    }
    int cur = 0;

    for (int jt = c; jt <= it; jt += SPLIT) {
        const int j0 = jt * 64;
        __syncthreads();   // K(jt) landed; prev tile's LDS reads done

        // prefetch K(jt+4) into spare buffer (async, crosses this tile)
        if (jt + SPLIT <= it) {
            const int j0n = (jt + SPLIT) * 64;
#pragma unroll
            for (int i = 0; i < 4; ++i) {
                int row = wave * 16 + i * 4 + krow;
                int chg = kchg ^ (row & 15);
                gld16(Kg + (size_t)(j0n + row) * H_DIM + chg * 8,
                      Ks[cur ^ 1] + (wave * 16 + i * 4) * 128);
            }
        }

        // issue all V fragment loads NOW; consumed in PV ~800 cy later
        bf16x8 vb[2][8];
#pragma unroll
        for (int kp = 0; kp < 2; ++kp)
#pragma unroll
            for (int nh = 0; nh < 8; ++nh)
                vb[kp][nh] = *reinterpret_cast<const bf16x8*>(
                    Vbase + (size_t)(nh * 16) * T_SEQ + j0 + kp * 32);

        // S = Q K^T (wave's 16 rows x 64 cols), K-dim = H = 128
        floatx4 s[4];
#pragma unroll
        for (int ni = 0; ni < 4; ++ni) s[ni] = floatx4{0.f, 0.f, 0.f, 0.f};
        __builtin_amdgcn_s_setprio(1);
#pragma unroll
        for (int kk = 0; kk < 4; ++kk)
#pragma unroll
            for (int ni = 0; ni < 4; ++ni) {
                bf16x8 kb = *reinterpret_cast<const bf16x8*>(
                    Ks[cur] + (ni * 16 + l15) * 128 + ((4 * kk + quad) ^ l15) * 8);
                s[ni] = __builtin_amdgcn_mfma_f32_16x16x32_bf16(q[kk], kb, s[ni], 0, 0, 0);
            }
        __builtin_amdgcn_s_setprio(0);

        if (jt == it) {   // causal mask, diagonal tile only
            int ii = i0 + wave * 16 + quad * 4;
#pragma unroll
            for (int ni = 0; ni < 4; ++ni) {
                int j = j0 + ni * 16 + l15;
#pragma unroll
                for (int r = 0; r < 4; ++r)
                    if (j > ii + r) s[ni][r] = -1e30f;
            }
        }

        // online softmax (rows = quad*4 + r; reduce across 16 l15 lanes)
        float alpha[4], rs[4];
#pragma unroll
        for (int r = 0; r < 4; ++r) {
            float v = fmaxf(fmaxf(s[0][r], s[1][r]), fmaxf(s[2][r], s[3][r]));
#pragma unroll
            for (int off = 8; off >= 1; off >>= 1)
                v = fmaxf(v, __shfl_xor(v, off, 64));
            float mn = fmaxf(m_i[r], v);
            alpha[r] = __expf(m_i[r] - mn);
            m_i[r] = mn;
            rs[r] = 0.f;
        }
#pragma unroll
        for (int ni = 0; ni < 4; ++ni)
#pragma unroll
            for (int r = 0; r < 4; ++r) {
                float p = __expf(s[ni][r] - m_i[r]);
                rs[r] += p;
                Pw[(quad * 4 + r) * P_STRIDE + ni * 16 + l15] = f2bf(p);
            }
#pragma unroll
        for (int r = 0; r < 4; ++r) {
            float v = rs[r];
#pragma unroll
            for (int off = 8; off >= 1; off >>= 1)
                v += __shfl_xor(v, off, 64);
            l_i[r] = l_i[r] * alpha[r] + v;
        }
#pragma unroll
        for (int nh = 0; nh < 8; ++nh)
#pragma unroll
            for (int r = 0; r < 4; ++r) o[nh][r] *= alpha[r];

        // O += P V : A-frag from per-wave LDS, B-frag from vb registers
        // (vmcnt wait lands here, ~800 cy after issue — overlapped).
#pragma unroll
        for (int kp = 0; kp < 2; ++kp) {
            bf16x8 a = *reinterpret_cast<const bf16x8*>(
                Pw + l15 * P_STRIDE + kp * 32 + quad * 8);
            __builtin_amdgcn_s_setprio(1);
#pragma unroll
            for (int nh = 0; nh < 8; ++nh)
                o[nh] = __builtin_amdgcn_mfma_f32_16x16x32_bf16(a, vb[kp][nh], o[nh], 0, 0, 0);
            __builtin_amdgcn_s_setprio(0);
        }

        cur ^= 1;
    }

    // write partials: O' (bf16, unnormalized) + m, l (fp32)
    const int idx = ((b * 64 + it) << 2) + c;
    ushort* po = partO + (size_t)idx * 64 * 128;
#pragma unroll
    for (int nh = 0; nh < 8; ++nh)
#pragma unroll
        for (int r = 0; r < 4; ++r) {
            int row = wave * 16 + quad * 4 + r;
            po[(size_t)row * 128 + nh * 16 + l15] = f2bf(o[nh][r]);
        }
    if (l15 == 0) {
        float* ml = partML + (size_t)idx * 128;
#pragma unroll
        for (int r = 0; r < 4; ++r) {
            int row = wave * 16 + quad * 4 + r;
            ml[row]      = m_i[r];
            ml[64 + row] = l_i[r];
        }
    }
}

// ---------------------------------------------------------------------------
// Kernel 3: combine partials (R11-exact): grid (256, 4), 16 out-rows/block.
// ---------------------------------------------------------------------------
__global__ __launch_bounds__(256) void combine(
    const ushort* __restrict__ partO, const float* __restrict__ partML,
    float* __restrict__ out) {
    const int it = blockIdx.x >> 2;
    const int qr = blockIdx.x & 3;
    const int b  = blockIdx.y;
    const int count = min(SPLIT, it + 1);
    const int tid = threadIdx.x;
    const int row = qr * 16 + (tid >> 4);      // 0..63 within group
    const int cg  = (tid & 15) * 8;            // 8 cols per thread
    const int base = (b * 64 + it) << 2;

    float m_c[SPLIT], l_c[SPLIT];
    float M = -1e30f;
    for (int cc = 0; cc < count; ++cc) {
        const float* ml = partML + (size_t)(base + cc) * 128;
        m_c[cc] = ml[row];
        l_c[cc] = ml[64 + row];
        M = fmaxf(M, m_c[cc]);
    }
    float L = 0.f, w[SPLIT];
    for (int cc = 0; cc < count; ++cc) {
        w[cc] = __expf(m_c[cc] - M);
        L += w[cc] * l_c[cc];
    }

    float acc[8];
#pragma unroll
    for (int j = 0; j < 8; ++j) acc[j] = 0.f;
    for (int cc = 0; cc < count; ++cc) {
        const ushort* po = partO + (size_t)(base + cc) * 8192 + (size_t)row * 128 + cg;
        uint4 v = *reinterpret_cast<const uint4*>(po);
        const ushort* pv = reinterpret_cast<const ushort*>(&v);
        float wc = w[cc];
#pragma unroll
        for (int e = 0; e < 8; ++e)
            acc[e] += wc * bf2f(pv[e]);
    }
    float invL = 1.0f / L;
    float* op = out + ((size_t)b * T_SEQ + it * 64 + row) * H_DIM + cg;
    float4 v0, v1;
    v0.x = acc[0] * invL; v0.y = acc[1] * invL;
    v0.z = acc[2] * invL; v0.w = acc[3] * invL;
    v1.x = acc[4] * invL; v1.y = acc[5] * invL;
    v1.z = acc[6] * invL; v1.w = acc[7] * invL;
    *reinterpret_cast<float4*>(op)     = v0;
    *reinterpret_cast<float4*>(op + 4) = v1;
}

// ---------------------------------------------------------------------------
extern "C" void kernel_launch(void* const* d_in, const int* in_sizes, int n_in,
                              void* d_out, int out_size, void* d_ws, size_t ws_size,
                              hipStream_t stream) {
    const float* x  = (const float*)d_in[0];
    const float* Wk = (const float*)d_in[1];
    const float* Wq = (const float*)d_in[2];
    const float* Wv = (const float*)d_in[3];

    ushort* kqv    = (ushort*)d_ws;
    ushort* wt     = kqv + (size_t)3 * M_ROWS * H_DIM;
    ushort* partO  = wt + (size_t)3 * H_DIM * C_EMB;
    float*  partML = (float*)(partO + (size_t)1024 * 64 * 128);

    transpose_w<<<dim3(16, 2, 3), 256, 0, stream>>>(Wk, Wq, Wv, wt);
    qkv_gemm<<<dim3(256), 512, 0, stream>>>(x, wt, kqv);
    flash_chunk<<<dim3(64 * SPLIT, NBATCH), 256, 0, stream>>>(kqv, partO, partML);
    combine<<<dim3(256, NBATCH), 256, 0, stream>>>(partO, partML, (float*)d_out);
}

// Round 14
// 177.414 us; speedup vs baseline: 1.3265x; 1.3265x over previous
//
#include <hip/hip_runtime.h>
#include <hip/hip_bf16.h>

// Problem constants (B=4, T=4096, C=1024, H=128)
#define T_SEQ 4096
#define NBATCH 4
#define C_EMB 1024
#define H_DIM 128
#define M_ROWS (NBATCH * T_SEQ)   // 16384
#define SPLIT 4                   // j-chunks per Q-tile (flash split-K)

typedef __bf16 bf16x8 __attribute__((ext_vector_type(8)));
typedef float  floatx4 __attribute__((ext_vector_type(4)));

__device__ __forceinline__ ushort f2bf(float f) {
    __hip_bfloat16 h = __float2bfloat16(f);
    return *reinterpret_cast<ushort*>(&h);
}
__device__ __forceinline__ float bf2f(ushort u) {
    unsigned int v = ((unsigned int)u) << 16;
    return *reinterpret_cast<float*>(&v);
}
__device__ __forceinline__ uint4 pack8(const float4& a, const float4& b) {
    __hip_bfloat162 h0 = __float22bfloat162_rn(make_float2(a.x, a.y));
    __hip_bfloat162 h1 = __float22bfloat162_rn(make_float2(a.z, a.w));
    __hip_bfloat162 h2 = __float22bfloat162_rn(make_float2(b.x, b.y));
    __hip_bfloat162 h3 = __float22bfloat162_rn(make_float2(b.z, b.w));
    uint4 r;
    r.x = *reinterpret_cast<unsigned int*>(&h0);
    r.y = *reinterpret_cast<unsigned int*>(&h1);
    r.z = *reinterpret_cast<unsigned int*>(&h2);
    r.w = *reinterpret_cast<unsigned int*>(&h3);
    return r;
}
// Async global->LDS, 16 B/lane. LDS dst is wave-uniform base + lane*16.
__device__ __forceinline__ void gld16(const ushort* g, ushort* l) {
    __builtin_amdgcn_global_load_lds(
        (const __attribute__((address_space(1))) unsigned int*)(g),
        (__attribute__((address_space(3))) unsigned int*)(l),
        16, 0, 0);
}

// ---------------------------------------------------------------------------
// Kernel 0: transpose weights fp32 [C][H] -> bf16 Wt[z][H][K=C]. (R12 tiled)
// ---------------------------------------------------------------------------
__global__ __launch_bounds__(256) void transpose_w(
    const float* __restrict__ Wk, const float* __restrict__ Wq,
    const float* __restrict__ Wv, ushort* __restrict__ wt) {
    const int z = blockIdx.z;
    const float* W = (z == 0) ? Wk : (z == 1) ? Wq : Wv;
    const int k0 = blockIdx.x * 64;
    const int n0 = blockIdx.y * 64;

    __shared__ ushort tile[64][72];   // [k-local][n-local], +8 pad

    const int tid = threadIdx.x;
    const int c4 = tid & 15;
    const int rg = tid >> 4;
#pragma unroll
    for (int i = 0; i < 4; ++i) {
        int r = rg * 4 + i;
        float4 v = *reinterpret_cast<const float4*>(
            W + (size_t)(k0 + r) * H_DIM + n0 + c4 * 4);
        tile[r][c4 * 4 + 0] = f2bf(v.x);
        tile[r][c4 * 4 + 1] = f2bf(v.y);
        tile[r][c4 * 4 + 2] = f2bf(v.z);
        tile[r][c4 * 4 + 3] = f2bf(v.w);
    }
    __syncthreads();
    ushort* Wtz = wt + (size_t)z * H_DIM * C_EMB;
#pragma unroll
    for (int o = 0; o < 2; ++o) {
        int linear = o * 256 + tid;        // [0,512)
        int nl = linear >> 3;              // 0..63
        int kc = linear & 7;               // uint4 chunk (8 k)
        ushort e[8];
#pragma unroll
        for (int j = 0; j < 8; ++j) e[j] = tile[kc * 8 + j][nl];
        uint4 pk;
        pk.x = (unsigned int)e[0] | ((unsigned int)e[1] << 16);
        pk.y = (unsigned int)e[2] | ((unsigned int)e[3] << 16);
        pk.z = (unsigned int)e[4] | ((unsigned int)e[5] << 16);
        pk.w = (unsigned int)e[6] | ((unsigned int)e[7] << 16);
        *reinterpret_cast<uint4*>(
            Wtz + (size_t)(n0 + nl) * C_EMB + k0 + kc * 8) = pk;
    }
}

// ---------------------------------------------------------------------------
// Kernel 1: fused QKV GEMM, 2-phase double-buffered staging (R5-exact,
// the 28.4 us measured version).
// ---------------------------------------------------------------------------
__global__ __launch_bounds__(512, 1) void qkv_gemm(
    const float* __restrict__ x, const ushort* __restrict__ wt,
    ushort* __restrict__ kqv) {
    const int m0 = blockIdx.x * 64;

    __shared__ ushort As[2][64 * 64];     // 2 x 8 KB
    __shared__ ushort Bs[2][384 * 64];    // 2 x 48 KB

    const int tid  = threadIdx.x;
    const int lane = tid & 63;
    const int wave = tid >> 6;          // 0..7
    const int l15  = lane & 15;
    const int quad = lane >> 4;
    const int mg   = (wave >> 1) * 16;  // m sub-block: 0/16/32/48
    const int nb   = (wave & 1) * 12;   // first 16-col n-block: 0 or 12

    floatx4 acc[12];
#pragma unroll
    for (int nj = 0; nj < 12; ++nj) acc[nj] = floatx4{0.f, 0.f, 0.f, 0.f};

    // A-path: thread covers row ar, chunk ac (8 floats per kt)
    const int ar = tid >> 3;            // 0..63
    const int ac = tid & 7;             // 0..7
    const int chp = ac ^ (ar & 7);      // XOR-swizzled chunk
    const float* xrow = x + (size_t)(m0 + ar) * C_EMB + ac * 8;

    // ---- prologue: stage kt=0 into buffer 0 ----
    float4 xa = *reinterpret_cast<const float4*>(xrow);
    float4 xb = *reinterpret_cast<const float4*>(xrow + 4);
#pragma unroll
    for (int i = 0; i < 6; ++i) {
        int rbase = wave * 48 + i * 8;
        int row = rbase + (lane >> 3);
        int chg = (lane & 7) ^ (row & 7);
        gld16(wt + (size_t)row * C_EMB + chg * 8, Bs[0] + rbase * 64);
    }
    *reinterpret_cast<uint4*>(As[0] + ar * 64 + chp * 8) = pack8(xa, xb);
    __syncthreads();   // drains vmcnt (B0) + lgkm (A0) -> buffer 0 ready
    // x regs for kt=1
    xa = *reinterpret_cast<const float4*>(xrow + 64);
    xb = *reinterpret_cast<const float4*>(xrow + 68);

    for (int kt = 0; kt < 16; ++kt) {
        const int cur = kt & 1;

        // ---- stage kt+1 into the other buffer (async; lands by next barrier)
        if (kt < 15) {
#pragma unroll
            for (int i = 0; i < 6; ++i) {
                int rbase = wave * 48 + i * 8;
                int row = rbase + (lane >> 3);
                int chg = (lane & 7) ^ (row & 7);
                gld16(wt + (size_t)row * C_EMB + (kt + 1) * 64 + chg * 8,
                      Bs[cur ^ 1] + rbase * 64);
            }
            // A: regs loaded during previous iteration's compute
            *reinterpret_cast<uint4*>(As[cur ^ 1] + ar * 64 + chp * 8) = pack8(xa, xb);
        }
        // issue x loads for kt+2 (latency hides under this kt's MFMA phase)
        if (kt < 14) {
            const float* nsrc = xrow + (kt + 2) * 64;
            xa = *reinterpret_cast<const float4*>(nsrc);
            xb = *reinterpret_cast<const float4*>(nsrc + 4);
        }

        // ---- compute on buffer cur ----
#pragma unroll
        for (int kk = 0; kk < 2; ++kk) {
            bf16x8 a = *reinterpret_cast<const bf16x8*>(
                As[cur] + (mg + l15) * 64 + ((4 * kk + quad) ^ (l15 & 7)) * 8);
#pragma unroll
            for (int nj = 0; nj < 12; ++nj) {
                int brow = (nb + nj) * 16 + l15;
                bf16x8 b = *reinterpret_cast<const bf16x8*>(
                    Bs[cur] + brow * 64 + ((4 * kk + quad) ^ (brow & 7)) * 8);
                acc[nj] = __builtin_amdgcn_mfma_f32_16x16x32_bf16(a, b, acc[nj], 0, 0, 0);
            }
        }

        __syncthreads();   // drains next tile's gld16 + ds_writes; reads done
    }

    // epilogue: z = gcol>>7 is uniform per nj (16-col blocks never straddle)
    const int rowb = m0 + mg + quad * 4;
#pragma unroll
    for (int nj = 0; nj < 12; ++nj) {
        int gcol = (nb + nj) * 16 + l15;
        int z = gcol >> 7;
        int cz = gcol & 127;
        if (z < 2) {
            const float scale = (z == 0) ? 0.03125f : 1.0f;   // fold C^-0.5 into k
            ushort* outz = kqv + (size_t)z * M_ROWS * H_DIM;
#pragma unroll
            for (int r = 0; r < 4; ++r)
                outz[(size_t)(rowb + r) * H_DIM + cz] = f2bf(acc[nj][r] * scale);
        } else {
            ushort* vt = kqv + (size_t)2 * M_ROWS * H_DIM;
            int bb   = rowb >> 12;
            int tloc = rowb & (T_SEQ - 1);
            ushort4 pk;
            pk.x = f2bf(acc[nj][0]);
            pk.y = f2bf(acc[nj][1]);
            pk.z = f2bf(acc[nj][2]);
            pk.w = f2bf(acc[nj][3]);
            *reinterpret_cast<ushort4*>(
                vt + ((size_t)(bb * H_DIM + cz) << 12) + tloc) = pk;
        }
    }
}

// ---------------------------------------------------------------------------
// Kernel 2: flash attention chunks (split-K), SKEWED 2-PHASE staging.
// Same 41 KB shell as the 59.4 us R12 version (Ks 16 + Vs 16 + Ps 9 KB,
// 3 blocks/CU, two barriers per tile) but K and V staging are skewed across
// the two barriers so each vmcnt drain is preceded by compute:
//   barrier A -> stage Vs(jt) -> QK^T (overlaps V staging) -> softmax
//   barrier B (drains Vs) -> stage Ks(jt+4) -> PV (overlaps K staging)
// Ks(jt+4) overwrites Ks(jt) — safe: QK^T reads finished at barrier B.
// R13 lesson: reg-staged V gets sunk by the compiler; gld16 is position-
// fixed. No new LDS, no new registers. LPT + T5 setprio kept.
// ---------------------------------------------------------------------------
#define P_STRIDE 72
__global__ __launch_bounds__(256, 3) void flash_chunk(
    const ushort* __restrict__ kqv, ushort* __restrict__ partO,
    float* __restrict__ partML) {
    const int it = 63 - (blockIdx.x >> 2);   // LPT: biggest chunks first
    const int c  = blockIdx.x & 3;
    if (c > it) return;                 // block-uniform early out
    const int b  = blockIdx.y;
    const int i0 = it * 64;

    const ushort* Qg = kqv + (size_t)b * T_SEQ * H_DIM;                          // k proj (query role)
    const ushort* Kg = kqv + (size_t)M_ROWS * H_DIM + (size_t)b * T_SEQ * H_DIM; // q proj (key role)
    const ushort* Vt = kqv + (size_t)2 * M_ROWS * H_DIM + (size_t)b * H_DIM * T_SEQ; // vT[h][t]

    __shared__ ushort Ks[64 * 128];      // 16 KB, row = 128 u (16 chunks)
    __shared__ ushort Vs[128 * 64];      // 16 KB, row = 64 u (8 chunks)
    __shared__ ushort Ps[4][16 * P_STRIDE];   // 9 KB

    const int tid  = threadIdx.x;
    const int lane = tid & 63;
    const int wave = tid >> 6;
    const int l15  = lane & 15;
    const int quad = lane >> 4;

    // Q fragments: row = i0 + wave*16 + l15, k = kk*32 + quad*8
    bf16x8 q[4];
    {
        const ushort* qrow = Qg + (size_t)(i0 + wave * 16 + l15) * H_DIM + quad * 8;
#pragma unroll
        for (int kk = 0; kk < 4; ++kk)
            q[kk] = *reinterpret_cast<const bf16x8*>(qrow + kk * 32);
    }

    float m_i[4], l_i[4];
#pragma unroll
    for (int r = 0; r < 4; ++r) { m_i[r] = -1e30f; l_i[r] = 0.f; }
    floatx4 o[8];
#pragma unroll
    for (int nh = 0; nh < 8; ++nh) o[nh] = floatx4{0.f, 0.f, 0.f, 0.f};

    ushort* Pw = Ps[wave];

    // staging helpers (macro-free, no lambdas capturing arrays)
    const int krow = lane >> 4;          // K: row-in-group
    const int kch  = lane & 15;          // K: chunk pre-XOR
    const int vrow = lane >> 3;          // V: row-in-group
    const int vch  = lane & 7;           // V: chunk pre-XOR

    // ---- prologue: stage Ks(c); drained at first barrier A ----
    {
        const int j0s = c * 64;
#pragma unroll
        for (int i = 0; i < 4; ++i) {
            int row = wave * 16 + i * 4 + krow;
            int chg = kch ^ (row & 15);
            gld16(Kg + (size_t)(j0s + row) * H_DIM + chg * 8,
                  Ks + (wave * 16 + i * 4) * 128);
        }
    }

    for (int jt = c; jt <= it; jt += SPLIT) {
        const int j0 = jt * 64;
        __syncthreads();   // A: drains Ks(jt) staging; prev PV's Vs reads done

        // stage Vs(jt) — drain happens at barrier B, under QK^T+softmax
#pragma unroll
        for (int i = 0; i < 4; ++i) {
            int row = wave * 32 + i * 8 + vrow;
            int chg = vch ^ (row & 7);
            gld16(Vt + (size_t)row * T_SEQ + j0 + chg * 8,
                  Vs + (wave * 32 + i * 8) * 64);
        }

        // S = Q K^T (wave's 16 rows x 64 cols), K-dim = H = 128
        floatx4 s[4];
#pragma unroll
        for (int ni = 0; ni < 4; ++ni) s[ni] = floatx4{0.f, 0.f, 0.f, 0.f};
        __builtin_amdgcn_s_setprio(1);
#pragma unroll
        for (int kk = 0; kk < 4; ++kk)
#pragma unroll
            for (int ni = 0; ni < 4; ++ni) {
                bf16x8 kb = *reinterpret_cast<const bf16x8*>(
                    Ks + (ni * 16 + l15) * 128 + ((4 * kk + quad) ^ l15) * 8);
                s[ni] = __builtin_amdgcn_mfma_f32_16x16x32_bf16(q[kk], kb, s[ni], 0, 0, 0);
            }
        __builtin_amdgcn_s_setprio(0);

        if (jt == it) {   // causal mask, diagonal tile only
            int ii = i0 + wave * 16 + quad * 4;
#pragma unroll
            for (int ni = 0; ni < 4; ++ni) {
                int j = j0 + ni * 16 + l15;
#pragma unroll
                for (int r = 0; r < 4; ++r)
                    if (j > ii + r) s[ni][r] = -1e30f;
            }
        }

        // online softmax (rows = quad*4 + r; reduce across 16 l15 lanes)
        float alpha[4], rs[4];
#pragma unroll
        for (int r = 0; r < 4; ++r) {
            float v = fmaxf(fmaxf(s[0][r], s[1][r]), fmaxf(s[2][r], s[3][r]));
#pragma unroll
            for (int off = 8; off >= 1; off >>= 1)
                v = fmaxf(v, __shfl_xor(v, off, 64));
            float mn = fmaxf(m_i[r], v);
            alpha[r] = __expf(m_i[r] - mn);
            m_i[r] = mn;
            rs[r] = 0.f;
        }
#pragma unroll
        for (int ni = 0; ni < 4; ++ni)
#pragma unroll
            for (int r = 0; r < 4; ++r) {
                float p = __expf(s[ni][r] - m_i[r]);
                rs[r] += p;
                Pw[(quad * 4 + r) * P_STRIDE + ni * 16 + l15] = f2bf(p);
            }
#pragma unroll
        for (int r = 0; r < 4; ++r) {
            float v = rs[r];
#pragma unroll
            for (int off = 8; off >= 1; off >>= 1)
                v += __shfl_xor(v, off, 64);
            l_i[r] = l_i[r] * alpha[r] + v;
        }
#pragma unroll
        for (int nh = 0; nh < 8; ++nh)
#pragma unroll
            for (int r = 0; r < 4; ++r) o[nh][r] *= alpha[r];

        __syncthreads();   // B: drains Vs(jt) staging; QK^T's Ks reads done

        // stage Ks(jt+4) into the SAME Ks buffer (safe: Ks reads finished).
        // Its drain happens at next iteration's barrier A, under PV below.
        if (jt + SPLIT <= it) {
            const int j0n = (jt + SPLIT) * 64;
#pragma unroll
            for (int i = 0; i < 4; ++i) {
                int row = wave * 16 + i * 4 + krow;
                int chg = kch ^ (row & 15);
                gld16(Kg + (size_t)(j0n + row) * H_DIM + chg * 8,
                      Ks + (wave * 16 + i * 4) * 128);
            }
        }

        // O += P V : A-frag from per-wave LDS (in-order within wave),
        // B-frag from swizzled Vs — overlaps the K staging above.
#pragma unroll
        for (int kp = 0; kp < 2; ++kp) {
            bf16x8 a = *reinterpret_cast<const bf16x8*>(
                Pw + l15 * P_STRIDE + kp * 32 + quad * 8);
            __builtin_amdgcn_s_setprio(1);
#pragma unroll
            for (int nh = 0; nh < 8; ++nh) {
                bf16x8 vb = *reinterpret_cast<const bf16x8*>(
                    Vs + (nh * 16 + l15) * 64 + ((4 * kp + quad) ^ (l15 & 7)) * 8);
                o[nh] = __builtin_amdgcn_mfma_f32_16x16x32_bf16(a, vb, o[nh], 0, 0, 0);
            }
            __builtin_amdgcn_s_setprio(0);
        }
    }

    // write partials: O' (bf16, unnormalized) + m, l (fp32)
    const int idx = ((b * 64 + it) << 2) + c;
    ushort* po = partO + (size_t)idx * 64 * 128;
#pragma unroll
    for (int nh = 0; nh < 8; ++nh)
#pragma unroll
        for (int r = 0; r < 4; ++r) {
            int row = wave * 16 + quad * 4 + r;
            po[(size_t)row * 128 + nh * 16 + l15] = f2bf(o[nh][r]);
        }
    if (l15 == 0) {
        float* ml = partML + (size_t)idx * 128;
#pragma unroll
        for (int r = 0; r < 4; ++r) {
            int row = wave * 16 + quad * 4 + r;
            ml[row]      = m_i[r];
            ml[64 + row] = l_i[r];
        }
    }
}

// ---------------------------------------------------------------------------
// Kernel 3: combine partials (R11-exact): grid (256, 4), 16 out-rows/block.
// ---------------------------------------------------------------------------
__global__ __launch_bounds__(256) void combine(
    const ushort* __restrict__ partO, const float* __restrict__ partML,
    float* __restrict__ out) {
    const int it = blockIdx.x >> 2;
    const int qr = blockIdx.x & 3;
    const int b  = blockIdx.y;
    const int count = min(SPLIT, it + 1);
    const int tid = threadIdx.x;
    const int row = qr * 16 + (tid >> 4);      // 0..63 within group
    const int cg  = (tid & 15) * 8;            // 8 cols per thread
    const int base = (b * 64 + it) << 2;

    float m_c[SPLIT], l_c[SPLIT];
    float M = -1e30f;
    for (int cc = 0; cc < count; ++cc) {
        const float* ml = partML + (size_t)(base + cc) * 128;
        m_c[cc] = ml[row];
        l_c[cc] = ml[64 + row];
        M = fmaxf(M, m_c[cc]);
    }
    float L = 0.f, w[SPLIT];
    for (int cc = 0; cc < count; ++cc) {
        w[cc] = __expf(m_c[cc] - M);
        L += w[cc] * l_c[cc];
    }

    float acc[8];
#pragma unroll
    for (int j = 0; j < 8; ++j) acc[j] = 0.f;
    for (int cc = 0; cc < count; ++cc) {
        const ushort* po = partO + (size_t)(base + cc) * 8192 + (size_t)row * 128 + cg;
        uint4 v = *reinterpret_cast<const uint4*>(po);
        const ushort* pv = reinterpret_cast<const ushort*>(&v);
        float wc = w[cc];
#pragma unroll
        for (int e = 0; e < 8; ++e)
            acc[e] += wc * bf2f(pv[e]);
    }
    float invL = 1.0f / L;
    float* op = out + ((size_t)b * T_SEQ + it * 64 + row) * H_DIM + cg;
    float4 v0, v1;
    v0.x = acc[0] * invL; v0.y = acc[1] * invL;
    v0.z = acc[2] * invL; v0.w = acc[3] * invL;
    v1.x = acc[4] * invL; v1.y = acc[5] * invL;
    v1.z = acc[6] * invL; v1.w = acc[7] * invL;
    *reinterpret_cast<float4*>(op)     = v0;
    *reinterpret_cast<float4*>(op + 4) = v1;
}

// ---------------------------------------------------------------------------
extern "C" void kernel_launch(void* const* d_in, const int* in_sizes, int n_in,
                              void* d_out, int out_size, void* d_ws, size_t ws_size,
                              hipStream_t stream) {
    const float* x  = (const float*)d_in[0];
    const float* Wk = (const float*)d_in[1];
    const float* Wq = (const float*)d_in[2];
    const float* Wv = (const float*)d_in[3];

    ushort* kqv    = (ushort*)d_ws;
    ushort* wt     = kqv + (size_t)3 * M_ROWS * H_DIM;
    ushort* partO  = wt + (size_t)3 * H_DIM * C_EMB;
    float*  partML = (float*)(partO + (size_t)1024 * 64 * 128);

    transpose_w<<<dim3(16, 2, 3), 256, 0, stream>>>(Wk, Wq, Wv, wt);
    qkv_gemm<<<dim3(256), 512, 0, stream>>>(x, wt, kqv);
    flash_chunk<<<dim3(64 * SPLIT, NBATCH), 256, 0, stream>>>(kqv, partO, partML);
    combine<<<dim3(256, NBATCH), 256, 0, stream>>>(partO, partML, (float*)d_out);
}